// Round 3
// baseline (375.381 us; speedup 1.0000x reference)
//
#include <hip/hip_runtime.h>
#include <math.h>

// Problem constants (from reference): B=4096 segments, D=256 features, O=4 outputs.
#define BDIM 256   // 4 waves of 64

typedef float v4f __attribute__((ext_vector_type(4)));

// ---------------------------------------------------------------------------
// Kernel 1: exclusive prefix sum of segment counts -> offsets (single block).
// B=4096, trivial cost (~16 KB read/write). Unchanged.
// ---------------------------------------------------------------------------
__global__ void seg_offsets_kernel(const int* __restrict__ counts,
                                   int* __restrict__ offsets, int B) {
  __shared__ int partial[BDIM];
  const int tid = threadIdx.x;
  const int chunk = (B + BDIM - 1) / BDIM;   // 16 for B=4096
  const int base = tid * chunk;

  int s = 0;
  for (int i = 0; i < chunk; ++i) {
    const int idx = base + i;
    if (idx < B) s += counts[idx];
  }
  partial[tid] = s;
  __syncthreads();

  // Hillis-Steele inclusive scan over the 256 per-thread partials.
  for (int off = 1; off < BDIM; off <<= 1) {
    int v = (tid >= off) ? partial[tid - off] : 0;
    __syncthreads();
    partial[tid] += v;
    __syncthreads();
  }

  int run = (tid == 0) ? 0 : partial[tid - 1];  // exclusive base for this chunk
  for (int i = 0; i < chunk; ++i) {
    const int idx = base + i;
    if (idx < B) {
      offsets[idx] = run;
      run += counts[idx];
    }
  }
}

// ---------------------------------------------------------------------------
// Kernel 2: fused segment-mean + projection + sigmoid.
// One WAVE per segment (4 segments / 256-thread block), no barriers, no LDS.
// R2 changes (memory path only; decomposition & FMA order unchanged):
//   - NO nontemporal hint: x may be LLC-resident across iterations (268 MB vs
//     256 MB L3); nt bypassed that entirely in R0/R1.
//   - 8-row ping-pong double buffer: 8 KB/wave in flight during FMAs (was
//     4 KB), with zero cross-buffer register copies (two-phase unrolled loop).
//   - Tail handled in 4/2/1 row chunks (batched load issue, not a dependent
//     per-row load->FMA chain).
// (R3 = R2 resubmitted verbatim: the R2 bench never executed — container
//  infra failure, no data. Isolate the variable; measure before changing.)
// ---------------------------------------------------------------------------
#define FMA_ROW(v)                                                   \
  do {                                                               \
    a0 += (v).x * w0.x + (v).y * w0.y + (v).z * w0.z + (v).w * w0.w; \
    a1 += (v).x * w1.x + (v).y * w1.y + (v).z * w1.z + (v).w * w1.w; \
    a2 += (v).x * w2.x + (v).y * w2.y + (v).z * w2.z + (v).w * w2.w; \
    a3 += (v).x * w3.x + (v).y * w3.y + (v).z * w3.z + (v).w * w3.w; \
  } while (0)

#define LOAD8(r0, r1, r2, r3, r4, r5, r6, r7, base) \
  do {                                              \
    r0 = (base)[0 * 64];                            \
    r1 = (base)[1 * 64];                            \
    r2 = (base)[2 * 64];                            \
    r3 = (base)[3 * 64];                            \
    r4 = (base)[4 * 64];                            \
    r5 = (base)[5 * 64];                            \
    r6 = (base)[6 * 64];                            \
    r7 = (base)[7 * 64];                            \
  } while (0)

__global__ __launch_bounds__(BDIM) void mean_proj_kernel(
    const float* __restrict__ x, const int* __restrict__ counts,
    const int* __restrict__ offsets, const float* __restrict__ W,
    const float* __restrict__ b, float* __restrict__ out, int B) {
  const int tid  = threadIdx.x;
  const int lane = tid & 63;
  const int wave = tid >> 6;                 // 0..3
  const int seg  = blockIdx.x * 4 + wave;    // one wave per segment
  if (seg >= B) return;                      // no barriers below -> safe

  const int  cnt   = counts[seg];
  const long start = (long)offsets[seg];

  // Each lane owns features [4*lane, 4*lane+4). W is [4][256] row-major.
  const v4f* W4 = (const v4f*)W;
  const v4f w0 = W4[0 * 64 + lane];
  const v4f w1 = W4[1 * 64 + lane];
  const v4f w2 = W4[2 * 64 + lane];
  const v4f w3 = W4[3 * 64 + lane];

  float a0 = 0.f, a1 = 0.f, a2 = 0.f, a3 = 0.f;

  // Row r (256 floats) = 64 v4f; this lane's slice at xb[r*64].
  const v4f* xb = (const v4f*)x + start * 64 + lane;

  int n = 0;
  const v4f* p = xb;                         // base of current 8-row group

  v4f A0, A1, A2, A3, A4, A5, A6, A7;
  v4f B0, B1, B2, B3, B4, B5, B6, B7;

  bool have = (n + 8 <= cnt);                // wave-uniform (cnt >= 32 anyway)
  if (have) LOAD8(A0, A1, A2, A3, A4, A5, A6, A7, p);

  while (have) {
    // ---- phase 1: prefetch group B (rows n+8..n+15), consume group A ----
    bool haveN = (n + 16 <= cnt);
    if (haveN) LOAD8(B0, B1, B2, B3, B4, B5, B6, B7, p + 512);
    FMA_ROW(A0); FMA_ROW(A1); FMA_ROW(A2); FMA_ROW(A3);
    FMA_ROW(A4); FMA_ROW(A5); FMA_ROW(A6); FMA_ROW(A7);
    n += 8; p += 512;
    if (!haveN) break;

    // ---- phase 2: prefetch group A (rows n+8..n+15), consume group B ----
    bool haveN2 = (n + 16 <= cnt);
    if (haveN2) LOAD8(A0, A1, A2, A3, A4, A5, A6, A7, p + 512);
    FMA_ROW(B0); FMA_ROW(B1); FMA_ROW(B2); FMA_ROW(B3);
    FMA_ROW(B4); FMA_ROW(B5); FMA_ROW(B6); FMA_ROW(B7);
    n += 8; p += 512;
    have = haveN2;
  }

  // ---- tail (<8 rows): batched 4/2/1 chunks, loads issued together ----
  if (n + 4 <= cnt) {
    v4f t0 = p[0 * 64], t1 = p[1 * 64], t2 = p[2 * 64], t3 = p[3 * 64];
    FMA_ROW(t0); FMA_ROW(t1); FMA_ROW(t2); FMA_ROW(t3);
    n += 4; p += 256;
  }
  if (n + 2 <= cnt) {
    v4f t0 = p[0 * 64], t1 = p[1 * 64];
    FMA_ROW(t0); FMA_ROW(t1);
    n += 2; p += 128;
  }
  if (n < cnt) {
    v4f t0 = p[0 * 64];
    FMA_ROW(t0);
  }

  // Wave-level butterfly reduction (64 lanes) -> lane 0 holds full dots.
  for (int off = 32; off > 0; off >>= 1) {
    a0 += __shfl_down(a0, off, 64);
    a1 += __shfl_down(a1, off, 64);
    a2 += __shfl_down(a2, off, 64);
    a3 += __shfl_down(a3, off, 64);
  }

  if (lane == 0) {
    const v4f bb = *(const v4f*)b;           // b is [4] f32, 16 B
    const float inv = 1.0f / (float)cnt;
    v4f r;
    r.x = 1.0f / (1.0f + expf(-(a0 * inv + bb.x)));
    r.y = 1.0f / (1.0f + expf(-(a1 * inv + bb.y)));
    r.z = 1.0f / (1.0f + expf(-(a2 * inv + bb.z)));
    r.w = 1.0f / (1.0f + expf(-(a3 * inv + bb.w)));
    *(v4f*)(out + (long)seg * 4) = r;        // 16 B aligned: seg*4 f32
  }
}

// ---------------------------------------------------------------------------
extern "C" void kernel_launch(void* const* d_in, const int* in_sizes, int n_in,
                              void* d_out, int out_size, void* d_ws, size_t ws_size,
                              hipStream_t stream) {
  const float* x        = (const float*)d_in[0];
  const int*   node_num = (const int*)d_in[1];   // int32 on device (JAX default)
  const float* W        = (const float*)d_in[2];
  const float* b        = (const float*)d_in[3];
  float*       out      = (float*)d_out;

  const int B = in_sizes[1];                     // 4096 segments
  int* offsets = (int*)d_ws;                     // 16 KB scratch

  seg_offsets_kernel<<<1, BDIM, 0, stream>>>(node_num, offsets, B);
  mean_proj_kernel<<<(B + 3) / 4, BDIM, 0, stream>>>(x, node_num, offsets, W, b,
                                                     out, B);
}